// Round 1
// baseline (1222.093 us; speedup 1.0000x reference)
//
#include <hip/hip_runtime.h>
#include <math.h>

#define NHEAD 8
#define HD    32
#define CEMB  256
#define NIN   2
#define BB    4
#define TT    8192
#define ROWS  32

__device__ __forceinline__ float groupMax32(float v) {
    v = fmaxf(v, __shfl_xor(v, 16, 32));
    v = fmaxf(v, __shfl_xor(v, 8, 32));
    v = fmaxf(v, __shfl_xor(v, 4, 32));
    v = fmaxf(v, __shfl_xor(v, 2, 32));
    v = fmaxf(v, __shfl_xor(v, 1, 32));
    return v;
}
__device__ __forceinline__ float groupSum32(float v) {
    v += __shfl_xor(v, 16, 32);
    v += __shfl_xor(v, 8, 32);
    v += __shfl_xor(v, 4, 32);
    v += __shfl_xor(v, 2, 32);
    v += __shfl_xor(v, 1, 32);
    return v;
}

// Pass A: k/v projection + softmax(k) + accumulate kv = k^T v and ksum = sum_t k
__global__ __launch_bounds__(256) void ka_kv(const float* __restrict__ y,
    const float* __restrict__ Wk, const float* __restrict__ bk,
    const float* __restrict__ Wv, const float* __restrict__ bv,
    float* __restrict__ kvws, float* __restrict__ ksws)
{
    __shared__ float ytile[ROWS][CEMB];
    const int i = blockIdx.z, b = blockIdx.y;
    const int row0 = blockIdx.x * ROWS;
    const int tid = threadIdx.x;
    const int c = tid;            // output column = h*32 + d
    const int h = c >> 5, d = c & 31;

    const float* yb = y + (((size_t)(i * BB + b)) * TT + row0) * CEMB;
    #pragma unroll
    for (int j = 0; j < (ROWS * CEMB) / (4 * 256); ++j) {
        int idx = tid + j * 256;
        int r = idx >> 6;
        int c4 = (idx & 63) << 2;
        *(float4*)&ytile[r][c4] = *(const float4*)&yb[(size_t)r * CEMB + c4];
    }
    __syncthreads();

    float acck[ROWS], accv[ROWS];
    #pragma unroll
    for (int r = 0; r < ROWS; ++r) { acck[r] = 0.f; accv[r] = 0.f; }

    const float* wk = Wk + (size_t)i * CEMB * CEMB + c;
    const float* wv = Wv + (size_t)i * CEMB * CEMB + c;
    for (int k4 = 0; k4 < CEMB / 4; ++k4) {
        const int k = k4 * 4;
        float wk0 = wk[(k+0)*CEMB], wk1 = wk[(k+1)*CEMB], wk2 = wk[(k+2)*CEMB], wk3 = wk[(k+3)*CEMB];
        float wv0 = wv[(k+0)*CEMB], wv1 = wv[(k+1)*CEMB], wv2 = wv[(k+2)*CEMB], wv3 = wv[(k+3)*CEMB];
        #pragma unroll
        for (int r = 0; r < ROWS; ++r) {
            float4 yv = *(const float4*)&ytile[r][k];
            acck[r] = fmaf(yv.x, wk0, acck[r]); acck[r] = fmaf(yv.y, wk1, acck[r]);
            acck[r] = fmaf(yv.z, wk2, acck[r]); acck[r] = fmaf(yv.w, wk3, acck[r]);
            accv[r] = fmaf(yv.x, wv0, accv[r]); accv[r] = fmaf(yv.y, wv1, accv[r]);
            accv[r] = fmaf(yv.z, wv2, accv[r]); accv[r] = fmaf(yv.w, wv3, accv[r]);
        }
    }
    const float bkc = bk[i * CEMB + c];
    const float bvc = bv[i * CEMB + c];

    float ksl = 0.f;
    float kva[HD];
    #pragma unroll
    for (int e2 = 0; e2 < HD; ++e2) kva[e2] = 0.f;

    #pragma unroll
    for (int r = 0; r < ROWS; ++r) {
        float lk = acck[r] + bkc;
        float lv = accv[r] + bvc;
        float m  = groupMax32(lk);
        float ex = __expf(lk - m);
        float s  = groupSum32(ex);
        float kval = ex / s;          // k[row r, head h, dim d]
        ksl += kval;
        #pragma unroll
        for (int e2 = 0; e2 < HD; ++e2)
            kva[e2] = fmaf(kval, __shfl(lv, e2, 32), kva[e2]);   // kv[d][e] += k_d * v_e
    }
    atomicAdd(&ksws[((i * BB + b) * NHEAD + h) * HD + d], ksl);
    float* kvp = kvws + ((((size_t)(i * BB + b)) * NHEAD + h) * HD + d) * HD;
    #pragma unroll
    for (int e2 = 0; e2 < HD; ++e2) atomicAdd(&kvp[e2], kva[e2]);
}

// Pass B: q projection + softmax + out_pre = q + sum_i (q@kv_i)*Dinv_i, then @Wp + bp
__global__ __launch_bounds__(256) void kb_out(const float* __restrict__ x,
    const float* __restrict__ Wq, const float* __restrict__ bq,
    const float* __restrict__ Wp, const float* __restrict__ bp,
    const float* __restrict__ kvws, const float* __restrict__ ksws,
    float* __restrict__ out)
{
    __shared__ float xt[ROWS][CEMB];   // x tile, later reused for out_pre
    const int b = blockIdx.y;
    const int row0 = blockIdx.x * ROWS;
    const int tid = threadIdx.x;
    const int c = tid;                 // output column = h*32 + e
    const int h = c >> 5, e = c & 31;

    const float* xb = x + ((size_t)b * TT + row0) * CEMB;
    #pragma unroll
    for (int j = 0; j < (ROWS * CEMB) / (4 * 256); ++j) {
        int idx = tid + j * 256;
        int r = idx >> 6;
        int c4 = (idx & 63) << 2;
        *(float4*)&xt[r][c4] = *(const float4*)&xb[(size_t)r * CEMB + c4];
    }
    __syncthreads();

    // kv columns (this thread's e) into registers: kvI[dd] = kv[i][b][h][dd][e]
    float kv0[HD], kv1[HD];
    {
        const float* p0 = kvws + (((size_t)(0 * BB + b) * NHEAD + h) * HD) * HD + e;
        const float* p1 = kvws + (((size_t)(1 * BB + b) * NHEAD + h) * HD) * HD + e;
        #pragma unroll
        for (int dd = 0; dd < HD; ++dd) { kv0[dd] = p0[dd * HD]; kv1[dd] = p1[dd * HD]; }
    }
    const float ks0 = ksws[((0 * BB + b) * NHEAD + h) * HD + e];
    const float ks1 = ksws[((1 * BB + b) * NHEAD + h) * HD + e];

    float acc[ROWS];
    #pragma unroll
    for (int r = 0; r < ROWS; ++r) acc[r] = 0.f;
    const float* wq = Wq + c;
    for (int k4 = 0; k4 < CEMB / 4; ++k4) {
        const int k = k4 * 4;
        float w0 = wq[(k+0)*CEMB], w1 = wq[(k+1)*CEMB], w2 = wq[(k+2)*CEMB], w3 = wq[(k+3)*CEMB];
        #pragma unroll
        for (int r = 0; r < ROWS; ++r) {
            float4 xv = *(const float4*)&xt[r][k];
            acc[r] = fmaf(xv.x, w0, acc[r]); acc[r] = fmaf(xv.y, w1, acc[r]);
            acc[r] = fmaf(xv.z, w2, acc[r]); acc[r] = fmaf(xv.w, w3, acc[r]);
        }
    }
    const float bqc = bq[c];

    #pragma unroll
    for (int r = 0; r < ROWS; ++r) {
        float lq = acc[r] + bqc;
        float m  = groupMax32(lq);
        float ex = __expf(lq - m);
        float s  = groupSum32(ex);
        float q  = ex / s;                       // q[r, head h, dim = lane&31]
        float den0 = groupSum32(q * ks0);        // sum_d q_d * ksum0_d
        float den1 = groupSum32(q * ks1);
        float o0 = 0.f, o1 = 0.f;
        #pragma unroll
        for (int dd = 0; dd < HD; ++dd) {
            float qd = __shfl(q, dd, 32);
            o0 = fmaf(qd, kv0[dd], o0);
            o1 = fmaf(qd, kv1[dd], o1);
        }
        acc[r] = q + o0 / den0 + o1 / den1;      // out_pre[r, c]
    }
    __syncthreads();
    #pragma unroll
    for (int r = 0; r < ROWS; ++r) xt[r][c] = acc[r];
    __syncthreads();

    float fa[ROWS];
    #pragma unroll
    for (int r = 0; r < ROWS; ++r) fa[r] = 0.f;
    const float* wp = Wp + c;
    for (int k4 = 0; k4 < CEMB / 4; ++k4) {
        const int k = k4 * 4;
        float w0 = wp[(k+0)*CEMB], w1 = wp[(k+1)*CEMB], w2 = wp[(k+2)*CEMB], w3 = wp[(k+3)*CEMB];
        #pragma unroll
        for (int r = 0; r < ROWS; ++r) {
            float4 ov = *(const float4*)&xt[r][k];
            fa[r] = fmaf(ov.x, w0, fa[r]); fa[r] = fmaf(ov.y, w1, fa[r]);
            fa[r] = fmaf(ov.z, w2, fa[r]); fa[r] = fmaf(ov.w, w3, fa[r]);
        }
    }
    const float bpc = bp[c];
    float* ob = out + ((size_t)b * TT + row0) * CEMB + c;
    #pragma unroll
    for (int r = 0; r < ROWS; ++r) ob[(size_t)r * CEMB] = fa[r] + bpc;
}

extern "C" void kernel_launch(void* const* d_in, const int* in_sizes, int n_in,
                              void* d_out, int out_size, void* d_ws, size_t ws_size,
                              hipStream_t stream)
{
    const float* x  = (const float*)d_in[0];
    const float* y  = (const float*)d_in[1];
    const float* Wq = (const float*)d_in[2];
    const float* bq = (const float*)d_in[3];
    const float* Wk = (const float*)d_in[4];
    const float* bk = (const float*)d_in[5];
    const float* Wv = (const float*)d_in[6];
    const float* bv = (const float*)d_in[7];
    const float* Wp = (const float*)d_in[8];
    const float* bp = (const float*)d_in[9];
    float* out = (float*)d_out;

    float* kvws = (float*)d_ws;                              // NIN*BB*NHEAD*HD*HD floats
    float* ksws = kvws + (size_t)NIN * BB * NHEAD * HD * HD; // NIN*BB*NHEAD*HD floats
    size_t zbytes = ((size_t)NIN * BB * NHEAD * HD * HD + (size_t)NIN * BB * NHEAD * HD) * sizeof(float);
    hipMemsetAsync(d_ws, 0, zbytes, stream);

    dim3 ga(TT / ROWS, BB, NIN);
    hipLaunchKernelGGL(ka_kv, ga, dim3(256), 0, stream, y, Wk, bk, Wv, bv, kvws, ksws);
    dim3 gb(TT / ROWS, BB);
    hipLaunchKernelGGL(kb_out, gb, dim3(256), 0, stream, x, Wq, bq, Wp, bp, kvws, ksws, out);
}

// Round 2
// 172.900 us; speedup vs baseline: 7.0682x; 7.0682x over previous
//
#include <hip/hip_runtime.h>
#include <math.h>

#define NHEAD 8
#define HD    32
#define CEMB  256
#define NIN   2
#define BB    4
#define TT    8192

typedef __attribute__((ext_vector_type(8))) short short8;
typedef __attribute__((ext_vector_type(4))) float f32x4;
typedef __attribute__((ext_vector_type(16))) float f32x16;

__device__ __forceinline__ unsigned short f2bf(float f) {
    union { float f; unsigned u; } v; v.f = f;
    unsigned u = v.u;
    return (unsigned short)((u + 0x7fffu + ((u >> 16) & 1u)) >> 16);
}
__device__ __forceinline__ float bf2f(unsigned short s) {
    union { unsigned u; float f; } v; v.u = ((unsigned)s) << 16;
    return v.f;
}

// ---- prep: convert + transpose all weights to bf16: Wt[n][k] = W[k][n] ----
__global__ __launch_bounds__(256) void prep_w(const float* __restrict__ Wq,
    const float* __restrict__ Wk, const float* __restrict__ Wv,
    const float* __restrict__ Wp, unsigned short* __restrict__ wsb)
{
    int gid = blockIdx.x * 256 + threadIdx.x;   // 6*65536
    int m = gid >> 16;
    int idx = gid & 65535;
    int n = idx >> 8, k = idx & 255;
    const float* src; unsigned short* dst;
    switch (m) {
        case 0: src = Wq;          dst = wsb;          break;
        case 1: src = Wk;          dst = wsb + 65536;  break;
        case 2: src = Wk + 65536;  dst = wsb + 131072; break;
        case 3: src = Wv;          dst = wsb + 196608; break;
        case 4: src = Wv + 65536;  dst = wsb + 262144; break;
        default: src = Wp;         dst = wsb + 327680; break;
    }
    dst[n * 256 + k] = f2bf(src[k * 256 + n]);
}

// ---- pass A: k/v projection (MFMA) + softmax + kv = k^T v (MFMA) -> partials ----
__global__ __launch_bounds__(256) void passA(const float* __restrict__ y,
    const float* __restrict__ bk, const float* __restrict__ bv,
    const unsigned short* __restrict__ Wkt, const unsigned short* __restrict__ Wvt,
    float* __restrict__ part)
{
    __shared__ unsigned short ytile[64][264];
    __shared__ unsigned short wt[64][264];
    __shared__ unsigned short kT[32][72];
    __shared__ unsigned short vT[32][72];
    __shared__ float ksl[NHEAD][HD];

    const int i = blockIdx.z, b = blockIdx.y, x0 = blockIdx.x;
    const int tid = threadIdx.x;
    const int wid = tid >> 6, lane = tid & 63;
    const int lg = lane >> 4, li = lane & 15;

    ksl[tid >> 5][tid & 31] = 0.f;

    f32x16 kvacc0 = {}; f32x16 kvacc1 = {};

    for (int iter = 0; iter < 2; ++iter) {
        const int row0 = (x0 + 64 * iter) * 64;
        __syncthreads();
        const float* yb = y + ((size_t)(i * BB + b) * TT + row0) * CEMB;
        #pragma unroll
        for (int j = 0; j < 16; ++j) {
            int idx = tid + j * 256;
            int r = idx >> 6, c4 = (idx & 63) << 2;
            float4 v4 = *(const float4*)&yb[(size_t)r * CEMB + c4];
            ushort4 p; p.x = f2bf(v4.x); p.y = f2bf(v4.y); p.z = f2bf(v4.z); p.w = f2bf(v4.w);
            *(ushort4*)&ytile[r][c4] = p;
        }
        for (int h = 0; h < NHEAD; ++h) {
            __syncthreads();
            #pragma unroll
            for (int j = 0; j < 8; ++j) {
                int idx = tid + j * 256;
                int r = idx >> 5, c8 = (idx & 31) << 3;
                const unsigned short* src = (r < 32)
                    ? (Wkt + ((size_t)(i * 256 + h * 32 + r)) * 256 + c8)
                    : (Wvt + ((size_t)(i * 256 + h * 32 + (r - 32))) * 256 + c8);
                *(short8*)&wt[r][c8] = *(const short8*)src;
            }
            __syncthreads();
            f32x4 acc0 = {}, acc1 = {}, acc2 = {}, acc3 = {};
            #pragma unroll
            for (int ks = 0; ks < 8; ++ks) {
                short8 af = *(const short8*)&ytile[16 * wid + li][ks * 32 + lg * 8];
                short8 b0 = *(const short8*)&wt[li][ks * 32 + lg * 8];
                short8 b1 = *(const short8*)&wt[16 + li][ks * 32 + lg * 8];
                short8 b2 = *(const short8*)&wt[32 + li][ks * 32 + lg * 8];
                short8 b3 = *(const short8*)&wt[48 + li][ks * 32 + lg * 8];
                acc0 = __builtin_amdgcn_mfma_f32_16x16x32_bf16(af, b0, acc0, 0, 0, 0);
                acc1 = __builtin_amdgcn_mfma_f32_16x16x32_bf16(af, b1, acc1, 0, 0, 0);
                acc2 = __builtin_amdgcn_mfma_f32_16x16x32_bf16(af, b2, acc2, 0, 0, 0);
                acc3 = __builtin_amdgcn_mfma_f32_16x16x32_bf16(af, b3, acc3, 0, 0, 0);
            }
            const float bk0 = bk[i * CEMB + h * 32 + li];
            const float bk1 = bk[i * CEMB + h * 32 + 16 + li];
            const float bv0 = bv[i * CEMB + h * 32 + li];
            const float bv1 = bv[i * CEMB + h * 32 + 16 + li];
            float kq0[4], kq1[4], vv0[4], vv1[4];
            float kss0 = 0.f, kss1 = 0.f;
            #pragma unroll
            for (int reg = 0; reg < 4; ++reg) {
                float l0 = acc0[reg] + bk0, l1 = acc1[reg] + bk1;
                float m = fmaxf(l0, l1);
                m = fmaxf(m, __shfl_xor(m, 1, 16));
                m = fmaxf(m, __shfl_xor(m, 2, 16));
                m = fmaxf(m, __shfl_xor(m, 4, 16));
                m = fmaxf(m, __shfl_xor(m, 8, 16));
                float e0 = __expf(l0 - m), e1 = __expf(l1 - m);
                float s = e0 + e1;
                s += __shfl_xor(s, 1, 16);
                s += __shfl_xor(s, 2, 16);
                s += __shfl_xor(s, 4, 16);
                s += __shfl_xor(s, 8, 16);
                float isv = 1.f / s;
                kq0[reg] = e0 * isv; kq1[reg] = e1 * isv;
                kss0 += kq0[reg];    kss1 += kq1[reg];
                vv0[reg] = acc2[reg] + bv0; vv1[reg] = acc3[reg] + bv1;
            }
            atomicAdd(&ksl[h][li], kss0);
            atomicAdd(&ksl[h][16 + li], kss1);
            {
                int t0 = 16 * wid + 4 * lg;
                ushort4 p;
                p.x = f2bf(kq0[0]); p.y = f2bf(kq0[1]); p.z = f2bf(kq0[2]); p.w = f2bf(kq0[3]);
                *(ushort4*)&kT[li][t0] = p;
                p.x = f2bf(kq1[0]); p.y = f2bf(kq1[1]); p.z = f2bf(kq1[2]); p.w = f2bf(kq1[3]);
                *(ushort4*)&kT[16 + li][t0] = p;
                p.x = f2bf(vv0[0]); p.y = f2bf(vv0[1]); p.z = f2bf(vv0[2]); p.w = f2bf(vv0[3]);
                *(ushort4*)&vT[li][t0] = p;
                p.x = f2bf(vv1[0]); p.y = f2bf(vv1[1]); p.z = f2bf(vv1[2]); p.w = f2bf(vv1[3]);
                *(ushort4*)&vT[16 + li][t0] = p;
            }
            __syncthreads();
            if (wid == (h & 3)) {
                int l31 = lane & 31, hk = lane >> 5;
                #pragma unroll
                for (int ts = 0; ts < 4; ++ts) {
                    short8 ka = *(const short8*)&kT[l31][ts * 16 + hk * 8];
                    short8 vb = *(const short8*)&vT[l31][ts * 16 + hk * 8];
                    if (h < 4) kvacc0 = __builtin_amdgcn_mfma_f32_32x32x16_bf16(ka, vb, kvacc0, 0, 0, 0);
                    else       kvacc1 = __builtin_amdgcn_mfma_f32_32x32x16_bf16(ka, vb, kvacc1, 0, 0, 0);
                }
            }
        }
    }
    __syncthreads();
    const size_t slot = (size_t)(i * BB + b) * 64 + x0;
    float* pb = part + slot * (NHEAD * 1056);
    const int l31 = lane & 31, hk = lane >> 5;
    #pragma unroll
    for (int reg = 0; reg < 16; ++reg) {
        int d = (reg & 3) + 8 * (reg >> 2) + 4 * hk;
        pb[(size_t)wid * 1056 + d * 32 + l31]       = kvacc0[reg];
        pb[(size_t)(wid + 4) * 1056 + d * 32 + l31] = kvacc1[reg];
    }
    { int h = tid >> 5, d = tid & 31; pb[(size_t)h * 1056 + 1024 + d] = ksl[h][d]; }
}

// ---- reduce partials -> kvt (bf16, transposed [e][d]) + ksum (fp32) ----
__global__ __launch_bounds__(256) void reduceKV(const float* __restrict__ part,
    unsigned short* __restrict__ kvt, float* __restrict__ ksum)
{
    const int g = blockIdx.x;        // (i*BB+b)*8 + h
    const int ib = g >> 3, h = g & 7;
    const int tid = threadIdx.x;
    for (int e = tid; e < 1056; e += 256) {
        float s = 0.f;
        const float* p = part + ((size_t)ib * 64 * NHEAD + h) * 1056 + e;
        for (int xx = 0; xx < 64; ++xx) s += p[(size_t)xx * NHEAD * 1056];
        if (e < 1024) {
            int d = e >> 5, eo = e & 31;
            kvt[((size_t)g * 32 + eo) * 32 + d] = f2bf(s);
        } else {
            ksum[(size_t)g * 32 + (e - 1024)] = s;
        }
    }
}

// ---- pass B: q proj + softmax + attn + out proj ----
__global__ __launch_bounds__(256) void passB(const float* __restrict__ x,
    const float* __restrict__ bq, const float* __restrict__ bp,
    const unsigned short* __restrict__ Wqt, const unsigned short* __restrict__ Wpt,
    const unsigned short* __restrict__ kvt, const float* __restrict__ ksum,
    float* __restrict__ out)
{
    __shared__ unsigned short xa[64][264];     // x tile, later reused as out_pre
    __shared__ unsigned short ql[64][264];
    __shared__ unsigned short wst[10240];
    __shared__ float dl[2][64][8];

    const int b = blockIdx.y, x0 = blockIdx.x;
    const int row0 = x0 * 64;
    const int tid = threadIdx.x;
    const int wid = tid >> 6, lane = tid & 63, lg = lane >> 4, li = lane & 15;

    const float* xb = x + ((size_t)b * TT + row0) * CEMB;
    #pragma unroll
    for (int j = 0; j < 16; ++j) {
        int idx = tid + j * 256;
        int r = idx >> 6, c4 = (idx & 63) << 2;
        float4 v4 = *(const float4*)&xb[(size_t)r * CEMB + c4];
        ushort4 p; p.x = f2bf(v4.x); p.y = f2bf(v4.y); p.z = f2bf(v4.z); p.w = f2bf(v4.w);
        *(ushort4*)&xa[r][c4] = p;
    }

    for (int h = 0; h < NHEAD; ++h) {
        __syncthreads();
        #pragma unroll
        for (int j = 0; j < 4; ++j) {
            int idx = tid + j * 256;
            int r = idx >> 5, c8 = (idx & 31) << 3;
            *(short8*)&wst[r * 264 + c8] = *(const short8*)(Wqt + ((size_t)(h * 32 + r)) * 256 + c8);
        }
        __syncthreads();
        f32x4 a0 = {}, a1 = {};
        #pragma unroll
        for (int ks = 0; ks < 8; ++ks) {
            short8 af = *(const short8*)&xa[16 * wid + li][ks * 32 + lg * 8];
            short8 b0 = *(const short8*)&wst[li * 264 + ks * 32 + lg * 8];
            short8 b1 = *(const short8*)&wst[(16 + li) * 264 + ks * 32 + lg * 8];
            a0 = __builtin_amdgcn_mfma_f32_16x16x32_bf16(af, b0, a0, 0, 0, 0);
            a1 = __builtin_amdgcn_mfma_f32_16x16x32_bf16(af, b1, a1, 0, 0, 0);
        }
        const float bq0 = bq[h * 32 + li], bq1 = bq[h * 32 + 16 + li];
        #pragma unroll
        for (int reg = 0; reg < 4; ++reg) {
            float l0 = a0[reg] + bq0, l1 = a1[reg] + bq1;
            float m = fmaxf(l0, l1);
            m = fmaxf(m, __shfl_xor(m, 1, 16));
            m = fmaxf(m, __shfl_xor(m, 2, 16));
            m = fmaxf(m, __shfl_xor(m, 4, 16));
            m = fmaxf(m, __shfl_xor(m, 8, 16));
            float e0 = __expf(l0 - m), e1 = __expf(l1 - m);
            float s = e0 + e1;
            s += __shfl_xor(s, 1, 16);
            s += __shfl_xor(s, 2, 16);
            s += __shfl_xor(s, 4, 16);
            s += __shfl_xor(s, 8, 16);
            float isv = 1.f / s;
            a0[reg] = e0 * isv; a1[reg] = e1 * isv;
        }
        #pragma unroll
        for (int reg = 0; reg < 4; ++reg) {
            int r = 16 * wid + 4 * lg + reg;
            ql[r][h * 32 + li]      = f2bf(a0[reg]);
            ql[r][h * 32 + 16 + li] = f2bf(a1[reg]);
        }
    }
    __syncthreads();

    // Dinv
    #pragma unroll
    for (int p = 0; p < 2; ++p) {
        int rh = tid + p * 256;
        int r = rh >> 3, h = rh & 7;
        const float* ks0 = ksum + ((size_t)(0 * BB + b) * 8 + h) * 32;
        const float* ks1 = ksum + ((size_t)(1 * BB + b) * 8 + h) * 32;
        float s0 = 0.f, s1 = 0.f;
        for (int d = 0; d < 32; ++d) {
            float qv = bf2f(ql[r][h * 32 + d]);
            s0 += qv * ks0[d]; s1 += qv * ks1[d];
        }
        dl[0][r][h] = 1.f / s0;
        dl[1][r][h] = 1.f / s1;
    }
    __syncthreads();

    // out_pre = q + sum_i attn_i * Dinv_i
    f32x4 of[16];
    #pragma unroll
    for (int nf = 0; nf < 16; ++nf)
        #pragma unroll
        for (int reg = 0; reg < 4; ++reg)
            of[nf][reg] = bf2f(ql[16 * wid + 4 * lg + reg][nf * 16 + li]);

    for (int ii = 0; ii < NIN; ++ii) {
        #pragma unroll
        for (int h = 0; h < NHEAD; ++h) {
            short8 af = *(const short8*)&ql[16 * wid + li][h * 32 + lg * 8];
            const unsigned short* kvb = kvt + ((size_t)((ii * BB + b) * 8 + h)) * 1024;
            short8 b0 = *(const short8*)(kvb + (size_t)li * 32 + lg * 8);
            short8 b1 = *(const short8*)(kvb + (size_t)(16 + li) * 32 + lg * 8);
            f32x4 z = {};
            f32x4 t0 = __builtin_amdgcn_mfma_f32_16x16x32_bf16(af, b0, z, 0, 0, 0);
            f32x4 t1 = __builtin_amdgcn_mfma_f32_16x16x32_bf16(af, b1, z, 0, 0, 0);
            #pragma unroll
            for (int reg = 0; reg < 4; ++reg) {
                float dv = dl[ii][16 * wid + 4 * lg + reg][h];
                of[2 * h][reg]     += t0[reg] * dv;
                of[2 * h + 1][reg] += t1[reg] * dv;
            }
        }
    }
    __syncthreads();
    #pragma unroll
    for (int nf = 0; nf < 16; ++nf)
        #pragma unroll
        for (int reg = 0; reg < 4; ++reg)
            xa[16 * wid + 4 * lg + reg][nf * 16 + li] = f2bf(of[nf][reg]);

    #pragma unroll
    for (int nf = 0; nf < 16; ++nf) of[nf] = (f32x4){};

    for (int ks = 0; ks < 8; ++ks) {
        __syncthreads();
        #pragma unroll
        for (int j = 0; j < 4; ++j) {
            int idx = tid + j * 256;
            int r = idx >> 2, c8 = (idx & 3) << 3;
            *(short8*)&wst[r * 40 + c8] = *(const short8*)(Wpt + (size_t)r * 256 + ks * 32 + c8);
        }
        __syncthreads();
        short8 af = *(const short8*)&xa[16 * wid + li][ks * 32 + lg * 8];
        #pragma unroll
        for (int nf = 0; nf < 16; ++nf) {
            short8 bfr = *(const short8*)&wst[(nf * 16 + li) * 40 + lg * 8];
            of[nf] = __builtin_amdgcn_mfma_f32_16x16x32_bf16(af, bfr, of[nf], 0, 0, 0);
        }
    }

    #pragma unroll
    for (int nf = 0; nf < 16; ++nf) {
        float bpc = bp[nf * 16 + li];
        #pragma unroll
        for (int reg = 0; reg < 4; ++reg) {
            int r = 16 * wid + 4 * lg + reg;
            out[((size_t)b * TT + row0 + r) * CEMB + nf * 16 + li] = of[nf][reg] + bpc;
        }
    }
}

extern "C" void kernel_launch(void* const* d_in, const int* in_sizes, int n_in,
                              void* d_out, int out_size, void* d_ws, size_t ws_size,
                              hipStream_t stream)
{
    const float* x  = (const float*)d_in[0];
    const float* y  = (const float*)d_in[1];
    const float* Wq = (const float*)d_in[2];
    const float* bq = (const float*)d_in[3];
    const float* Wk = (const float*)d_in[4];
    const float* bk = (const float*)d_in[5];
    const float* Wv = (const float*)d_in[6];
    const float* bv = (const float*)d_in[7];
    const float* Wp = (const float*)d_in[8];
    const float* bp = (const float*)d_in[9];
    float* out = (float*)d_out;

    unsigned short* wsb = (unsigned short*)d_ws;
    // short offsets: Wqt 0, Wkt 65536, Wvt 196608, Wpt 327680 (end 393216 shorts = 768KB)
    float* part = (float*)((char*)d_ws + 786432);                       // 512*8*1056 f32 = 17.3MB
    unsigned short* kvt = (unsigned short*)((char*)d_ws + 18087936);    // 64*1024 bf16
    float* ksum = (float*)((char*)d_ws + 18219008);                     // 64*32 f32

    hipLaunchKernelGGL(prep_w, dim3(1536), dim3(256), 0, stream, Wq, Wk, Wv, Wp, wsb);
    hipLaunchKernelGGL(passA, dim3(64, BB, NIN), dim3(256), 0, stream,
                       y, bk, bv, wsb + 65536, wsb + 196608, part);
    hipLaunchKernelGGL(reduceKV, dim3(64), dim3(256), 0, stream, part, kvt, ksum);
    hipLaunchKernelGGL(passB, dim3(128, BB), dim3(256), 0, stream,
                       x, bq, bp, wsb + 0, wsb + 327680, kvt, ksum, out);
}

// Round 3
// 165.274 us; speedup vs baseline: 7.3943x; 1.0461x over previous
//
#include <hip/hip_runtime.h>
#include <math.h>

#define NHEAD 8
#define CEMB  256
#define NIN   2
#define BB    4
#define TT    8192

typedef __attribute__((ext_vector_type(8))) short short8;
typedef __attribute__((ext_vector_type(4))) float f32x4;
typedef __attribute__((ext_vector_type(16))) float f32x16;

__device__ __forceinline__ unsigned short f2bf(float f) {
    union { float f; unsigned u; } v; v.f = f;
    unsigned u = v.u;
    return (unsigned short)((u + 0x7fffu + ((u >> 16) & 1u)) >> 16);
}
__device__ __forceinline__ float bf2f(unsigned short s) {
    union { unsigned u; float f; } v; v.u = ((unsigned)s) << 16;
    return v.f;
}

// ---- prep: convert + transpose all weights to bf16: Wt[n][k] = W[k][n] ----
__global__ __launch_bounds__(256) void prep_w(const float* __restrict__ Wq,
    const float* __restrict__ Wk, const float* __restrict__ Wv,
    const float* __restrict__ Wp, unsigned short* __restrict__ wsb)
{
    int gid = blockIdx.x * 256 + threadIdx.x;   // 6*65536
    int m = gid >> 16;
    int idx = gid & 65535;
    int n = idx >> 8, k = idx & 255;
    const float* src; unsigned short* dst;
    switch (m) {
        case 0: src = Wq;          dst = wsb;          break;
        case 1: src = Wk;          dst = wsb + 65536;  break;
        case 2: src = Wk + 65536;  dst = wsb + 131072; break;
        case 3: src = Wv;          dst = wsb + 196608; break;
        case 4: src = Wv + 65536;  dst = wsb + 262144; break;
        default: src = Wp;         dst = wsb + 327680; break;
    }
    dst[n * 256 + k] = f2bf(src[k * 256 + n]);
}

// ---- pass A: wave-per-2-heads k/v proj + softmax + kv = k^T v -> partials ----
__global__ __launch_bounds__(256, 2) void passA(const float* __restrict__ y,
    const float* __restrict__ bk, const float* __restrict__ bv,
    const unsigned short* __restrict__ Wkt, const unsigned short* __restrict__ Wvt,
    float* __restrict__ part)
{
    __shared__ unsigned short ytile[64][264];
    __shared__ unsigned short trK[4][32][72];
    __shared__ unsigned short trV[4][32][72];

    const int i = blockIdx.z, b = blockIdx.y, x0 = blockIdx.x;
    const int tid = threadIdx.x;
    const int wid = tid >> 6, lane = tid & 63;
    const int lg = lane >> 4, li = lane & 15;
    const int l31 = lane & 31, hk = lane >> 5;
    const int h0 = 2 * wid;

    float bk0[2], bk1[2], bv0[2], bv1[2];
    #pragma unroll
    for (int hh = 0; hh < 2; ++hh) {
        bk0[hh] = bk[i * CEMB + (h0 + hh) * 32 + li];
        bk1[hh] = bk[i * CEMB + (h0 + hh) * 32 + 16 + li];
        bv0[hh] = bv[i * CEMB + (h0 + hh) * 32 + li];
        bv1[hh] = bv[i * CEMB + (h0 + hh) * 32 + 16 + li];
    }

    // per-lane weight row pointers for the 8 col-tiles (k h0|k h1|v h0|v h1, 2 tiles each)
    const unsigned short* wrow[8];
    #pragma unroll
    for (int ct = 0; ct < 8; ++ct) {
        int hh = (ct >> 1) & 1, sub = ct & 1;
        const unsigned short* W = (ct < 4) ? Wkt : Wvt;
        wrow[ct] = W + ((size_t)(i * 256 + (h0 + hh) * 32 + sub * 16 + li)) * 256 + lg * 8;
    }

    f32x16 kvacc0 = {}, kvacc1 = {};
    float ksa0[2] = {0.f, 0.f}, ksa1[2] = {0.f, 0.f};

    for (int iter = 0; iter < 2; ++iter) {
        __syncthreads();
        const int row0 = x0 * 128 + iter * 64;
        const float* yb = y + ((size_t)(i * BB + b) * TT + row0) * CEMB;
        #pragma unroll
        for (int j = 0; j < 16; ++j) {
            int idx = tid + j * 256;
            int r = idx >> 6, c4 = (idx & 63) << 2;
            float4 v4 = *(const float4*)&yb[(size_t)r * CEMB + c4];
            ushort4 p; p.x = f2bf(v4.x); p.y = f2bf(v4.y); p.z = f2bf(v4.z); p.w = f2bf(v4.w);
            *(ushort4*)&ytile[r][c4] = p;
        }
        __syncthreads();

        f32x4 acc[4][8];
        #pragma unroll
        for (int rt = 0; rt < 4; ++rt)
            #pragma unroll
            for (int ct = 0; ct < 8; ++ct) acc[rt][ct] = (f32x4){};

        #pragma unroll 2
        for (int ks = 0; ks < 8; ++ks) {
            short8 a0 = *(const short8*)&ytile[li][ks * 32 + lg * 8];
            short8 a1 = *(const short8*)&ytile[16 + li][ks * 32 + lg * 8];
            short8 a2 = *(const short8*)&ytile[32 + li][ks * 32 + lg * 8];
            short8 a3 = *(const short8*)&ytile[48 + li][ks * 32 + lg * 8];
            #pragma unroll
            for (int ct = 0; ct < 8; ++ct) {
                short8 bf = *(const short8*)(wrow[ct] + ks * 32);
                acc[0][ct] = __builtin_amdgcn_mfma_f32_16x16x32_bf16(a0, bf, acc[0][ct], 0, 0, 0);
                acc[1][ct] = __builtin_amdgcn_mfma_f32_16x16x32_bf16(a1, bf, acc[1][ct], 0, 0, 0);
                acc[2][ct] = __builtin_amdgcn_mfma_f32_16x16x32_bf16(a2, bf, acc[2][ct], 0, 0, 0);
                acc[3][ct] = __builtin_amdgcn_mfma_f32_16x16x32_bf16(a3, bf, acc[3][ct], 0, 0, 0);
            }
        }

        #pragma unroll
        for (int hh = 0; hh < 2; ++hh) {
            unsigned short (*kT)[72] = trK[wid];
            unsigned short (*vT)[72] = trV[wid];
            #pragma unroll
            for (int rt = 0; rt < 4; ++rt) {
                float kq0[4], kq1[4], vv0[4], vv1[4];
                #pragma unroll
                for (int reg = 0; reg < 4; ++reg) {
                    float l0 = acc[rt][2 * hh][reg] + bk0[hh];
                    float l1 = acc[rt][2 * hh + 1][reg] + bk1[hh];
                    float m = fmaxf(l0, l1);
                    m = fmaxf(m, __shfl_xor(m, 1, 16));
                    m = fmaxf(m, __shfl_xor(m, 2, 16));
                    m = fmaxf(m, __shfl_xor(m, 4, 16));
                    m = fmaxf(m, __shfl_xor(m, 8, 16));
                    float e0 = __expf(l0 - m), e1 = __expf(l1 - m);
                    float s = e0 + e1;
                    s += __shfl_xor(s, 1, 16);
                    s += __shfl_xor(s, 2, 16);
                    s += __shfl_xor(s, 4, 16);
                    s += __shfl_xor(s, 8, 16);
                    float isv = 1.f / s;
                    kq0[reg] = e0 * isv; kq1[reg] = e1 * isv;
                    ksa0[hh] += kq0[reg]; ksa1[hh] += kq1[reg];
                    vv0[reg] = acc[rt][4 + 2 * hh][reg] + bv0[hh];
                    vv1[reg] = acc[rt][5 + 2 * hh][reg] + bv1[hh];
                }
                ushort4 p;
                p.x = f2bf(kq0[0]); p.y = f2bf(kq0[1]); p.z = f2bf(kq0[2]); p.w = f2bf(kq0[3]);
                *(ushort4*)&kT[li][16 * rt + 4 * lg] = p;
                p.x = f2bf(kq1[0]); p.y = f2bf(kq1[1]); p.z = f2bf(kq1[2]); p.w = f2bf(kq1[3]);
                *(ushort4*)&kT[16 + li][16 * rt + 4 * lg] = p;
                p.x = f2bf(vv0[0]); p.y = f2bf(vv0[1]); p.z = f2bf(vv0[2]); p.w = f2bf(vv0[3]);
                *(ushort4*)&vT[li][16 * rt + 4 * lg] = p;
                p.x = f2bf(vv1[0]); p.y = f2bf(vv1[1]); p.z = f2bf(vv1[2]); p.w = f2bf(vv1[3]);
                *(ushort4*)&vT[16 + li][16 * rt + 4 * lg] = p;
            }
            // same-wave LDS RAW: ensure transpose writes complete before fragment reads
            asm volatile("s_waitcnt lgkmcnt(0)" ::: "memory");
            #pragma unroll
            for (int ts = 0; ts < 4; ++ts) {
                short8 ka = *(const short8*)&kT[l31][ts * 16 + hk * 8];
                short8 vb = *(const short8*)&vT[l31][ts * 16 + hk * 8];
                if (hh == 0) kvacc0 = __builtin_amdgcn_mfma_f32_32x32x16_bf16(ka, vb, kvacc0, 0, 0, 0);
                else         kvacc1 = __builtin_amdgcn_mfma_f32_32x32x16_bf16(ka, vb, kvacc1, 0, 0, 0);
            }
        }
    }

    const size_t slot = (size_t)(i * BB + b) * 64 + x0;
    float* pbase = part + slot * (NHEAD * 1056);
    #pragma unroll
    for (int hh = 0; hh < 2; ++hh) {
        float* pb = pbase + (size_t)(h0 + hh) * 1056;
        #pragma unroll
        for (int reg = 0; reg < 16; ++reg) {
            int d = (reg & 3) + 8 * (reg >> 2) + 4 * hk;
            pb[d * 32 + l31] = hh ? kvacc1[reg] : kvacc0[reg];
        }
        float s0 = ksa0[hh], s1 = ksa1[hh];
        s0 += __shfl_xor(s0, 16, 64); s0 += __shfl_xor(s0, 32, 64);
        s1 += __shfl_xor(s1, 16, 64); s1 += __shfl_xor(s1, 32, 64);
        if (lg == 0) { pb[1024 + li] = s0; pb[1024 + 16 + li] = s1; }
    }
}

// ---- reduce partials -> kvt (bf16, [e][d]) + ksum (fp32) ----
__global__ __launch_bounds__(256) void reduceKV(const float* __restrict__ part,
    unsigned short* __restrict__ kvt, float* __restrict__ ksum)
{
    const int g = blockIdx.y, ech = blockIdx.x;
    const int ib = g >> 3, h = g & 7;
    const int tid = threadIdx.x;
    const int e0 = ech * 264;
    const int e1 = (e0 + 264 < 1056) ? e0 + 264 : 1056;
    for (int e = e0 + tid; e < e1; e += 256) {
        float s = 0.f;
        const float* p = part + ((size_t)ib * 64 * NHEAD + h) * 1056 + e;
        #pragma unroll 4
        for (int xx = 0; xx < 64; ++xx) s += p[(size_t)xx * NHEAD * 1056];
        if (e < 1024) kvt[(size_t)g * 1024 + (e & 31) * 32 + (e >> 5)] = f2bf(s);
        else          ksum[(size_t)g * 32 + (e - 1024)] = s;
    }
}

// ---- pass B: q proj + softmax + attn + out proj (weights from global) ----
__global__ __launch_bounds__(256, 2) void passB(const float* __restrict__ x,
    const float* __restrict__ bq, const float* __restrict__ bp,
    const unsigned short* __restrict__ Wqt, const unsigned short* __restrict__ Wpt,
    const unsigned short* __restrict__ kvt, const float* __restrict__ ksum,
    float* __restrict__ out)
{
    __shared__ unsigned short xa[64][264];     // x tile, later reused as out_pre
    __shared__ unsigned short ql[64][264];
    __shared__ float dl[2][64][8];

    const int b = blockIdx.y, x0 = blockIdx.x;
    const int row0 = x0 * 64;
    const int tid = threadIdx.x;
    const int wid = tid >> 6, lane = tid & 63, lg = lane >> 4, li = lane & 15;
    const int h0 = 2 * wid;

    const float* xb = x + ((size_t)b * TT + row0) * CEMB;
    #pragma unroll
    for (int j = 0; j < 16; ++j) {
        int idx = tid + j * 256;
        int r = idx >> 6, c4 = (idx & 63) << 2;
        float4 v4 = *(const float4*)&xb[(size_t)r * CEMB + c4];
        ushort4 p; p.x = f2bf(v4.x); p.y = f2bf(v4.y); p.z = f2bf(v4.z); p.w = f2bf(v4.w);
        *(ushort4*)&xa[r][c4] = p;
    }
    __syncthreads();

    // q projection: wave owns heads h0, h0+1 (4 col-tiles)
    const unsigned short* qrow[4];
    #pragma unroll
    for (int ct = 0; ct < 4; ++ct)
        qrow[ct] = Wqt + ((size_t)((h0 + (ct >> 1)) * 32 + (ct & 1) * 16 + li)) * 256 + lg * 8;

    f32x4 qa[4][4];
    #pragma unroll
    for (int rt = 0; rt < 4; ++rt)
        #pragma unroll
        for (int ct = 0; ct < 4; ++ct) qa[rt][ct] = (f32x4){};

    #pragma unroll 2
    for (int ks = 0; ks < 8; ++ks) {
        short8 a0 = *(const short8*)&xa[li][ks * 32 + lg * 8];
        short8 a1 = *(const short8*)&xa[16 + li][ks * 32 + lg * 8];
        short8 a2 = *(const short8*)&xa[32 + li][ks * 32 + lg * 8];
        short8 a3 = *(const short8*)&xa[48 + li][ks * 32 + lg * 8];
        #pragma unroll
        for (int ct = 0; ct < 4; ++ct) {
            short8 bf = *(const short8*)(qrow[ct] + ks * 32);
            qa[0][ct] = __builtin_amdgcn_mfma_f32_16x16x32_bf16(a0, bf, qa[0][ct], 0, 0, 0);
            qa[1][ct] = __builtin_amdgcn_mfma_f32_16x16x32_bf16(a1, bf, qa[1][ct], 0, 0, 0);
            qa[2][ct] = __builtin_amdgcn_mfma_f32_16x16x32_bf16(a2, bf, qa[2][ct], 0, 0, 0);
            qa[3][ct] = __builtin_amdgcn_mfma_f32_16x16x32_bf16(a3, bf, qa[3][ct], 0, 0, 0);
        }
    }
    #pragma unroll
    for (int hh = 0; hh < 2; ++hh) {
        const float bq0 = bq[(h0 + hh) * 32 + li];
        const float bq1 = bq[(h0 + hh) * 32 + 16 + li];
        #pragma unroll
        for (int rt = 0; rt < 4; ++rt) {
            #pragma unroll
            for (int reg = 0; reg < 4; ++reg) {
                float l0 = qa[rt][2 * hh][reg] + bq0;
                float l1 = qa[rt][2 * hh + 1][reg] + bq1;
                float m = fmaxf(l0, l1);
                m = fmaxf(m, __shfl_xor(m, 1, 16));
                m = fmaxf(m, __shfl_xor(m, 2, 16));
                m = fmaxf(m, __shfl_xor(m, 4, 16));
                m = fmaxf(m, __shfl_xor(m, 8, 16));
                float e0 = __expf(l0 - m), e1 = __expf(l1 - m);
                float s = e0 + e1;
                s += __shfl_xor(s, 1, 16);
                s += __shfl_xor(s, 2, 16);
                s += __shfl_xor(s, 4, 16);
                s += __shfl_xor(s, 8, 16);
                float isv = 1.f / s;
                int r = 16 * rt + 4 * lg + reg;
                ql[r][(h0 + hh) * 32 + li]      = f2bf(e0 * isv);
                ql[r][(h0 + hh) * 32 + 16 + li] = f2bf(e1 * isv);
            }
        }
    }
    __syncthreads();

    // Dinv
    #pragma unroll
    for (int p = 0; p < 2; ++p) {
        int rh = tid + p * 256;
        int r = rh >> 3, h = rh & 7;
        const float* ks0 = ksum + ((size_t)(0 * BB + b) * 8 + h) * 32;
        const float* ks1 = ksum + ((size_t)(1 * BB + b) * 8 + h) * 32;
        float s0 = 0.f, s1 = 0.f;
        for (int d = 0; d < 32; ++d) {
            float qv = bf2f(ql[r][h * 32 + d]);
            s0 += qv * ks0[d]; s1 += qv * ks1[d];
        }
        dl[0][r][h] = 1.f / s0;
        dl[1][r][h] = 1.f / s1;
    }
    __syncthreads();

    // out_pre = q + sum_i attn_i * Dinv_i  (wave handles its 16-row slice, all cols)
    f32x4 of[16];
    #pragma unroll
    for (int nf = 0; nf < 16; ++nf)
        #pragma unroll
        for (int reg = 0; reg < 4; ++reg)
            of[nf][reg] = bf2f(ql[16 * wid + 4 * lg + reg][nf * 16 + li]);

    for (int ii = 0; ii < NIN; ++ii) {
        #pragma unroll
        for (int h = 0; h < NHEAD; ++h) {
            short8 af = *(const short8*)&ql[16 * wid + li][h * 32 + lg * 8];
            const unsigned short* kvb = kvt + ((size_t)((ii * BB + b) * 8 + h)) * 1024;
            short8 b0 = *(const short8*)(kvb + (size_t)li * 32 + lg * 8);
            short8 b1 = *(const short8*)(kvb + (size_t)(16 + li) * 32 + lg * 8);
            f32x4 z = {};
            f32x4 t0 = __builtin_amdgcn_mfma_f32_16x16x32_bf16(af, b0, z, 0, 0, 0);
            f32x4 t1 = __builtin_amdgcn_mfma_f32_16x16x32_bf16(af, b1, z, 0, 0, 0);
            #pragma unroll
            for (int reg = 0; reg < 4; ++reg) {
                float dv = dl[ii][16 * wid + 4 * lg + reg][h];
                of[2 * h][reg]     += t0[reg] * dv;
                of[2 * h + 1][reg] += t1[reg] * dv;
            }
        }
    }
    // write out_pre into xa (own 16-row slice only -> wave-local, fence suffices)
    #pragma unroll
    for (int nf = 0; nf < 16; ++nf)
        #pragma unroll
        for (int reg = 0; reg < 4; ++reg)
            xa[16 * wid + 4 * lg + reg][nf * 16 + li] = f2bf(of[nf][reg]);
    asm volatile("s_waitcnt lgkmcnt(0)" ::: "memory");

    #pragma unroll
    for (int nf = 0; nf < 16; ++nf) of[nf] = (f32x4){};

    const unsigned short* prow[16];
    #pragma unroll
    for (int nf = 0; nf < 16; ++nf)
        prow[nf] = Wpt + ((size_t)(nf * 16 + li)) * 256 + lg * 8;

    #pragma unroll 2
    for (int ks = 0; ks < 8; ++ks) {
        short8 af = *(const short8*)&xa[16 * wid + li][ks * 32 + lg * 8];
        #pragma unroll
        for (int nf = 0; nf < 16; ++nf) {
            short8 bfr = *(const short8*)(prow[nf] + ks * 32);
            of[nf] = __builtin_amdgcn_mfma_f32_16x16x32_bf16(af, bfr, of[nf], 0, 0, 0);
        }
    }

    #pragma unroll
    for (int nf = 0; nf < 16; ++nf) {
        float bpc = bp[nf * 16 + li];
        #pragma unroll
        for (int reg = 0; reg < 4; ++reg) {
            int r = 16 * wid + 4 * lg + reg;
            out[((size_t)b * TT + row0 + r) * CEMB + nf * 16 + li] = of[nf][reg] + bpc;
        }
    }
}

extern "C" void kernel_launch(void* const* d_in, const int* in_sizes, int n_in,
                              void* d_out, int out_size, void* d_ws, size_t ws_size,
                              hipStream_t stream)
{
    const float* x  = (const float*)d_in[0];
    const float* y  = (const float*)d_in[1];
    const float* Wq = (const float*)d_in[2];
    const float* bq = (const float*)d_in[3];
    const float* Wk = (const float*)d_in[4];
    const float* bk = (const float*)d_in[5];
    const float* Wv = (const float*)d_in[6];
    const float* bv = (const float*)d_in[7];
    const float* Wp = (const float*)d_in[8];
    const float* bp = (const float*)d_in[9];
    float* out = (float*)d_out;

    unsigned short* wsb = (unsigned short*)d_ws;
    // short offsets: Wqt 0, Wkt 65536, Wvt 196608, Wpt 327680 (end 393216 shorts = 768KB)
    float* part = (float*)((char*)d_ws + 786432);                       // 512*8*1056 f32 = 17.3MB
    unsigned short* kvt = (unsigned short*)((char*)d_ws + 18087936);    // 64*1024 bf16
    float* ksum = (float*)((char*)d_ws + 18219008);                     // 64*32 f32

    hipLaunchKernelGGL(prep_w, dim3(1536), dim3(256), 0, stream, Wq, Wk, Wv, Wp, wsb);
    hipLaunchKernelGGL(passA, dim3(64, BB, NIN), dim3(256), 0, stream,
                       y, bk, bv, wsb + 65536, wsb + 196608, part);
    hipLaunchKernelGGL(reduceKV, dim3(4, 64), dim3(256), 0, stream, part, kvt, ksum);
    hipLaunchKernelGGL(passB, dim3(128, BB), dim3(256), 0, stream,
                       x, bq, bp, wsb + 0, wsb + 327680, kvt, ksum, out);
}